// Round 7
// baseline (547.677 us; speedup 1.0000x reference)
//
#include <hip/hip_runtime.h>
#include <hip/hip_bf16.h>
#include <math.h>

// LAES deep readout, v5.1 (v5 resubmit; r6 bench was a container infra failure).
//   h_T = sum_{j<64} (x[511-j]-bias) @ G_j,  G_j = A^T (B^T)^j  (rho(B)~0.64)
// j = 32a+b:  h = Y0 + Y1@P32,  Y_a = sum_b xr_{32a+b} @ G_b.
// Ghat (=G^T=B^j A) stack built by 5 doubling levels; each level does L-GEMM
// (Ghat_{[m,2m)} = Phat_m @ G_j rows) and S-GEMM (Phat_2m = Phat_m^2) as ONE
// launch via row-split B-operand, epilogue routed by col in the reduce.
// fp32 from bf16 MFMA by hi/lo split (3 terms, lo*lo dropped).
// GEMM: 128x128 tile, 4 waves 2x2, 4x4 16x16x32 frags, BK=32.
// Staging: 8x global_load_lds dwordx4 per thread per chunk into linear
// [128][32] LDS planes (m97 structure); 16B-block XOR swizzle baked into the
// per-lane GLOBAL src address (LDS linear, read applies same XOR) -> 4-way
// instead of 8-way bank conflicts. No VALU extract anywhere in the K-loop.

typedef __attribute__((ext_vector_type(8))) short short8;
typedef __attribute__((ext_vector_type(4))) float f32x4;
typedef unsigned short u16;
typedef __attribute__((ext_vector_type(4))) unsigned short u16x4;

namespace {
constexpr int kB = 512, kH = 1024, kC = 10;
}

// ---- bf16 split helpers (verified r2-r5: absmax 0.0039 pass) ----
__device__ __forceinline__ unsigned bf16rn(float f) {
  unsigned u = __builtin_bit_cast(unsigned, f);
  return (u + 0x7fffu + ((u >> 16) & 1u)) >> 16;
}
__device__ __forceinline__ unsigned splitpack(float f) {  // lo<<16 | hi
  unsigned hi = bf16rn(f);
  float fh = __builtin_bit_cast(float, hi << 16);
  unsigned lo = bf16rn(f - fh);
  return (hi & 0xffffu) | (lo << 16);
}
__device__ __forceinline__ void split4(float4 v, u16x4& h, u16x4& l) {
  unsigned p0 = splitpack(v.x), p1 = splitpack(v.y), p2 = splitpack(v.z), p3 = splitpack(v.w);
  h = (u16x4){(u16)(p0 & 0xffffu), (u16)(p1 & 0xffffu), (u16)(p2 & 0xffffu), (u16)(p3 & 0xffffu)};
  l = (u16x4){(u16)(p0 >> 16), (u16)(p1 >> 16), (u16)(p2 >> 16), (u16)(p3 >> 16)};
}

// ---- async 16B global -> LDS ----
__device__ __forceinline__ void gll16(const u16* g, u16* l) {
  __builtin_amdgcn_global_load_lds(
      (const __attribute__((address_space(1))) void*)g,
      (__attribute__((address_space(3))) void*)l, 16, 0, 0);
}

// ---- fused flat packs: A->GP[:,0:128], B->PhA, W1->W1p, W2->W2p (hi/lo planes) ----
__global__ void laes_pack_flat(const float* __restrict__ A, const float* __restrict__ B,
                               const float* __restrict__ W1, const float* __restrict__ W2,
                               u16* __restrict__ GPh, u16* __restrict__ GPl,
                               u16* __restrict__ PhAh, u16* __restrict__ PhAl,
                               u16* __restrict__ W1h, u16* __restrict__ W1l,
                               u16* __restrict__ W2h, u16* __restrict__ W2l) {
  int i4 = (blockIdx.x * 256 + threadIdx.x) * 4;
  const float* src; u16 *dh, *dl; int r, c, ld;
  if (i4 < 131072) {
    r = i4 >> 7; c = i4 & 127; src = A + i4; dh = GPh; dl = GPl; ld = 4096;
  } else if (i4 < 131072 + 1048576) {
    int t = i4 - 131072; r = t >> 10; c = t & 1023; src = B + t; dh = PhAh; dl = PhAl; ld = 1024;
  } else if (i4 < 131072 + 2097152) {
    int t = i4 - 131072 - 1048576; r = t >> 10; c = t & 1023; src = W1 + t; dh = W1h; dl = W1l; ld = 1024;
  } else {
    int t = i4 - 131072 - 2097152; r = t >> 10; c = t & 1023; src = W2 + t; dh = W2h; dl = W2l; ld = 1024;
  }
  float4 v = *(const float4*)src;
  u16x4 h, l; split4(v, h, l);
  *(u16x4*)(dh + (size_t)r * ld + c) = h;
  *(u16x4*)(dl + (size_t)r * ld + c) = l;
}

// ---- transposed pack: out[c][r] = split(in[r][c]); in [R][C]; grid (C/32, R/32) ----
__global__ void laes_pack_tr(const float* __restrict__ in,
                             u16* __restrict__ oh, u16* __restrict__ ol,
                             int R, int C, int ldo) {
  __shared__ float t[32][33];
  int c0 = blockIdx.x * 32, r0 = blockIdx.y * 32;
  int tx = threadIdx.x, ty = threadIdx.y;  // block (32,8)
  #pragma unroll
  for (int i = 0; i < 4; ++i) {
    int r = ty + i * 8;
    t[r][tx] = in[(size_t)(r0 + r) * C + c0 + tx];
  }
  __syncthreads();
  #pragma unroll
  for (int i = 0; i < 4; ++i) {
    int r = ty + i * 8;
    unsigned p = splitpack(t[tx][r]);
    oh[(size_t)(c0 + r) * ldo + r0 + tx] = (u16)(p & 0xffffu);
    ol[(size_t)(c0 + r) * ldo + r0 + tx] = (u16)(p >> 16);
  }
}

// ---- Xb[a*512+m][32a+b slot] = split(x[511-(32a+b)][m][i]-bias[i]); grid (4,1024) ----
__global__ void laes_xprep(const float* __restrict__ x, const float* __restrict__ bias,
                           u16* __restrict__ Xh, u16* __restrict__ Xl) {
  int row = blockIdx.y;                   // 0..1023
  int a = row >> 9, m = row & 511;
  int k = (blockIdx.x * 256 + threadIdx.x) * 4;  // 0..4095
  int b = k >> 7, i = k & 127;
  int j = 32 * a + b;
  float4 v = *(const float4*)(x + ((size_t)(511 - j) * kB + m) * 128 + i);
  float4 bv = *(const float4*)(bias + i);
  float4 d = make_float4(v.x - bv.x, v.y - bv.y, v.z - bv.z, v.w - bv.w);
  u16x4 h, l; split4(d, h, l);
  *(u16x4*)(Xh + (size_t)row * 4096 + k) = h;
  *(u16x4*)(Xl + (size_t)row * 4096 + k) = l;
}

// ---- GEMM: C = A @ Bop^T, 128x128 tile, 4 waves 2x2, 4x4 frags, BK=32.
// hi/lo plane operands, global_load_lds staging, partials out. ----
__global__ __launch_bounds__(256, 2) void laes_gemm4(
    const u16* __restrict__ Ahi, const u16* __restrict__ Alo, int lda,
    const u16* __restrict__ B1h, const u16* __restrict__ B1l, int ldb1,
    const u16* __restrict__ B2h, const u16* __restrict__ B2l, int ldb2, int Nsplit,
    int gx, int N, int ksegLen,
    float* __restrict__ part, long long partStride) {
  __shared__ u16 sAh[4096], sAl[4096], sBh[4096], sBl[4096];  // [128][32] linear
  const int tid = threadIdx.x;
  const int lane = tid & 63, wave = tid >> 6;
  const int wr = wave >> 1, wc = wave & 1;
  const int l15 = lane & 15, q = lane >> 4;

  const int T = gridDim.x;
  const int bid = blockIdx.x;
  const int t = ((T & 7) == 0) ? ((bid & 7) * (T >> 3) + (bid >> 3)) : bid;  // XCD swizzle
  const int tm = t % gx, tn = t / gx;
  const int row0 = tm * 128, col0 = tn * 128;
  const int z = blockIdx.y;
  const int kbeg = z * ksegLen;

  const u16* Ah = Ahi + (size_t)row0 * lda;
  const u16* Al = Alo + (size_t)row0 * lda;
  const u16 *Bh, *Bl; int ldb;
  if (col0 < Nsplit) { Bh = B1h + (size_t)col0 * ldb1; Bl = B1l + (size_t)col0 * ldb1; ldb = ldb1; }
  else { Bh = B2h + (size_t)(col0 - Nsplit) * ldb2; Bl = B2l + (size_t)(col0 - Nsplit) * ldb2; ldb = ldb2; }

  // staging geometry: issue (wave, i) covers tile rows [(wave*2+i)*16, +16),
  // lane covers row +(lane>>2), 16B block (lane&3); global block XOR-swizzled.
  const int rsub = lane >> 2;
  const int sblk = (lane & 3) ^ (rsub & 3);
  const size_t roA0 = (size_t)(wave * 32 + rsub) * lda + sblk * 8;
  const size_t roA1 = roA0 + (size_t)16 * lda;
  const size_t roB0 = (size_t)(wave * 32 + rsub) * ldb + sblk * 8;
  const size_t roB1 = roB0 + (size_t)16 * ldb;
  const int ldsSeg = wave * 1024;  // elems; +512 for i=1

  f32x4 acc[4][4];
  #pragma unroll
  for (int mf = 0; mf < 4; ++mf)
    #pragma unroll
    for (int nf = 0; nf < 4; ++nf) acc[mf][nf] = (f32x4){0.f, 0.f, 0.f, 0.f};

  const int nch = ksegLen >> 5;
  const int sw3 = l15 & 3;
  const int koff = ((q ^ sw3) << 3);  // read-side XOR matches global pre-swizzle

  for (int ch = 0; ch < nch; ++ch) {
    const int kb = kbeg + ch * 32;
    gll16(Ah + roA0 + kb, sAh + ldsSeg);
    gll16(Al + roA0 + kb, sAl + ldsSeg);
    gll16(Bh + roB0 + kb, sBh + ldsSeg);
    gll16(Bl + roB0 + kb, sBl + ldsSeg);
    gll16(Ah + roA1 + kb, sAh + ldsSeg + 512);
    gll16(Al + roA1 + kb, sAl + ldsSeg + 512);
    gll16(Bh + roB1 + kb, sBh + ldsSeg + 512);
    gll16(Bl + roB1 + kb, sBl + ldsSeg + 512);
    __syncthreads();  // drains vmcnt (gll) for all waves

    short8 bh[4], bl[4];
    #pragma unroll
    for (int nf = 0; nf < 4; ++nf) {
      int off = (wc * 64 + nf * 16 + l15) * 32 + koff;
      bh[nf] = *(const short8*)&sBh[off];
      bl[nf] = *(const short8*)&sBl[off];
    }
    #pragma unroll
    for (int mf = 0; mf < 4; ++mf) {
      int off = (wr * 64 + mf * 16 + l15) * 32 + koff;
      short8 ah = *(const short8*)&sAh[off];
      short8 al = *(const short8*)&sAl[off];
      #pragma unroll
      for (int nf = 0; nf < 4; ++nf) {
        acc[mf][nf] = __builtin_amdgcn_mfma_f32_16x16x32_bf16(ah, bh[nf], acc[mf][nf], 0, 0, 0);
        acc[mf][nf] = __builtin_amdgcn_mfma_f32_16x16x32_bf16(ah, bl[nf], acc[mf][nf], 0, 0, 0);
        acc[mf][nf] = __builtin_amdgcn_mfma_f32_16x16x32_bf16(al, bh[nf], acc[mf][nf], 0, 0, 0);
      }
    }
    __syncthreads();
  }

  float* pz = part + (size_t)z * partStride;
  #pragma unroll
  for (int mf = 0; mf < 4; ++mf) {
    const int rowb = row0 + wr * 64 + mf * 16 + q * 4;
    #pragma unroll
    for (int nf = 0; nf < 4; ++nf) {
      const int col = col0 + wc * 64 + nf * 16 + l15;
      #pragma unroll
      for (int r = 0; r < 4; ++r)
        pz[(size_t)(rowb + r) * N + col] = acc[mf][nf][r];
    }
  }
}

// ---- split-K reduce + finalize. mode: 1 plane-normal, 2 plane-transposed,
// 4 tanh(+bias), 8 f32-out, 16 +addend(f32, ld N). Col routing at Nsplit. ----
__global__ void laes_reduce3(const float* __restrict__ part, int mn, int S, int N, int Nsplit,
                             int mode, const float* __restrict__ bias,
                             const float* __restrict__ addend,
                             u16* __restrict__ Ngh, u16* __restrict__ Ngl, int ldNg,
                             u16* __restrict__ Tgh, u16* __restrict__ Tgl, int ldTg,
                             u16* __restrict__ Nph, u16* __restrict__ Npl, int ldNp,
                             u16* __restrict__ Tph, u16* __restrict__ Tpl, int ldTp,
                             float* __restrict__ oF, int ldF) {
  int i4 = (blockIdx.x * 256 + threadIdx.x) * 4;
  if (i4 >= mn) return;
  float4 s = *(const float4*)(part + i4);
  for (int zz = 1; zz < S; ++zz) {
    float4 v = *(const float4*)(part + (size_t)zz * mn + i4);
    s.x += v.x; s.y += v.y; s.z += v.z; s.w += v.w;
  }
  int row = i4 / N, col = i4 - row * N;
  if (mode & 16) {
    float4 a = *(const float4*)(addend + (size_t)row * N + col);
    s.x += a.x; s.y += a.y; s.z += a.z; s.w += a.w;
  }
  if (mode & 4) {
    float4 b = *(const float4*)(bias + col);
    s.x = tanhf(s.x + b.x); s.y = tanhf(s.y + b.y);
    s.z = tanhf(s.z + b.z); s.w = tanhf(s.w + b.w);
  }
  u16 *nh, *nl, *th, *tl; int ldN, ldT, c = col;
  if (col < Nsplit) { nh = Ngh; nl = Ngl; ldN = ldNg; th = Tgh; tl = Tgl; ldT = ldTg; }
  else { c = col - Nsplit; nh = Nph; nl = Npl; ldN = ldNp; th = Tph; tl = Tpl; ldT = ldTp; }
  if (mode & 1) {
    u16x4 h, l; split4(s, h, l);
    *(u16x4*)(nh + (size_t)row * ldN + c) = h;
    *(u16x4*)(nl + (size_t)row * ldN + c) = l;
  }
  if (mode & 2) {
    float sv[4] = {s.x, s.y, s.z, s.w};
    #pragma unroll
    for (int j = 0; j < 4; ++j) {
      unsigned p = splitpack(sv[j]);
      th[(size_t)(c + j) * ldT + row] = (u16)(p & 0xffffu);
      tl[(size_t)(c + j) * ldT + row] = (u16)(p >> 16);
    }
  }
  if (mode & 8) *(float4*)(oF + (size_t)row * ldF + col) = s;
}

// ---- final linear layer, N=10, fp32 VALU ----
__global__ void laes_final(const float* __restrict__ h2, const float* __restrict__ W3,
                           const float* __restrict__ b3, float* __restrict__ outp) {
  const int b = blockIdx.x, lane = threadIdx.x;  // 1 wave
  float acc[kC];
  #pragma unroll
  for (int c = 0; c < kC; ++c) acc[c] = 0.f;
  for (int k = lane; k < kH; k += 64) {
    const float hv = h2[(size_t)b * kH + k];
    #pragma unroll
    for (int c = 0; c < kC; ++c) acc[c] += hv * W3[(size_t)c * kH + k];
  }
  #pragma unroll
  for (int c = 0; c < kC; ++c) {
    float v = acc[c];
    #pragma unroll
    for (int off = 32; off > 0; off >>= 1) v += __shfl_down(v, off);
    if (lane == 0) outp[(size_t)b * kC + c] = v + b3[c];
  }
}

extern "C" void kernel_launch(void* const* d_in, const int* in_sizes, int n_in,
                              void* d_out, int out_size, void* d_ws, size_t ws_size,
                              hipStream_t stream) {
  (void)in_sizes; (void)n_in; (void)out_size; (void)ws_size;
  const float* x    = (const float*)d_in[0];
  const float* Amat = (const float*)d_in[1];
  const float* Bmat = (const float*)d_in[2];
  const float* bias = (const float*)d_in[3];
  const float* W1   = (const float*)d_in[4];
  const float* b1   = (const float*)d_in[5];
  const float* W2   = (const float*)d_in[6];
  const float* b2   = (const float*)d_in[7];
  const float* W3   = (const float*)d_in[8];
  const float* b3   = (const float*)d_in[9];
  float* out = (float*)d_out;

  // ---- workspace: u16 plane region (~80MB) then f32 region (~56MB) ----
  u16* w = (u16*)d_ws;
  auto takeU = [&](size_t n) { u16* p = w; w += n; return p; };
  u16* GPh = takeU((size_t)1024 * 4096); u16* GPl = takeU((size_t)1024 * 4096);
  u16* GTh = takeU((size_t)4096 * 1024); u16* GTl = takeU((size_t)4096 * 1024);
  u16* PhAh = takeU((size_t)1024 * 1024); u16* PhAl = takeU((size_t)1024 * 1024);
  u16* PtAh = takeU((size_t)1024 * 1024); u16* PtAl = takeU((size_t)1024 * 1024);
  u16* PhBh = takeU((size_t)1024 * 1024); u16* PhBl = takeU((size_t)1024 * 1024);
  u16* PtBh = takeU((size_t)1024 * 1024); u16* PtBl = takeU((size_t)1024 * 1024);
  u16* W1h = takeU((size_t)1024 * 1024); u16* W1l = takeU((size_t)1024 * 1024);
  u16* W2h = takeU((size_t)1024 * 1024); u16* W2l = takeU((size_t)1024 * 1024);
  u16* Xbh = takeU((size_t)1024 * 4096); u16* Xbl = takeU((size_t)1024 * 4096);
  u16* Yh  = takeU((size_t)1024 * 1024); u16* Yl  = takeU((size_t)1024 * 1024);
  u16* hph = takeU((size_t)512 * 1024);  u16* hpl = takeU((size_t)512 * 1024);
  u16* h1h = takeU((size_t)512 * 1024);  u16* h1l = takeU((size_t)512 * 1024);
  float* fw = (float*)w;
  float* Yf   = fw; fw += (size_t)1024 * 1024;
  float* h2f  = fw; fw += (size_t)512 * 1024;
  float* part = fw;                      // max 4 x 1024 x 3072 = 12.6M floats

  auto gemm = [&](const u16* Aph, const u16* Apl, int lda,
                  const u16* B1ph, const u16* B1pl, int ldb1,
                  const u16* B2ph, const u16* B2pl, int ldb2, int Nsplit,
                  int M, int N, int K, int SK) {
    int gx = M / 128, gy = N / 128;
    laes_gemm4<<<dim3(gx * gy, SK), 256, 0, stream>>>(
        Aph, Apl, lda, B1ph, B1pl, ldb1, B2ph, B2pl, ldb2, Nsplit,
        gx, N, K / SK, part, (long long)M * N);
  };
  auto reduce = [&](int M, int N, int SK, int Nsplit, int mode,
                    const float* bp, const float* ad,
                    u16* ngh, u16* ngl, int ldNg, u16* tgh, u16* tgl, int ldTg,
                    u16* nph, u16* npl, int ldNp, u16* tph, u16* tpl, int ldTp,
                    float* oF, int ldF) {
    int mn = M * N;
    laes_reduce3<<<mn / 1024, 256, 0, stream>>>(part, mn, SK, N, Nsplit, mode, bp, ad,
                                                ngh, ngl, ldNg, tgh, tgl, ldTg,
                                                nph, npl, ldNp, tph, tpl, ldTp, oF, ldF);
  };

  // ---- prep ----
  laes_pack_flat<<<3200, 256, 0, stream>>>(Amat, Bmat, W1, W2,
                                           GPh, GPl, PhAh, PhAl, W1h, W1l, W2h, W2l);
  laes_pack_tr<<<dim3(4, 32), dim3(32, 8), 0, stream>>>(Amat, GTh, GTl, 1024, 128, 1024);
  laes_pack_tr<<<dim3(32, 32), dim3(32, 8), 0, stream>>>(Bmat, PtAh, PtAl, 1024, 1024, 1024);
  laes_xprep<<<dim3(4, 1024), 256, 0, stream>>>(x, bias, Xbh, Xbl);

  // ---- 5 merged doubling levels: out cols [0,128m) = Ghat_{[m,2m)}, rest = Phat_2m ----
  struct Lv { u16 *Phh, *Phl, *Pth, *Ptl, *POh, *POl, *TOh, *TOl; int m, SK; };
  const Lv lv[5] = {
    {PhAh, PhAl, PtAh, PtAl, PhBh, PhBl, PtBh, PtBl, 1, 8},
    {PhBh, PhBl, PtBh, PtBl, PhAh, PhAl, PtAh, PtAl, 2, 8},
    {PhAh, PhAl, PtAh, PtAl, PhBh, PhBl, PtBh, PtBl, 4, 8},
    {PhBh, PhBl, PtBh, PtBl, PhAh, PhAl, PtAh, PtAl, 8, 4},
    {PhAh, PhAl, PtAh, PtAl, PhBh, PhBl, PtBh, PtBl, 16, 4}};
  for (int i = 0; i < 5; ++i) {
    const int m = lv[i].m, Ns = 128 * m, N = Ns + 1024;
    gemm(lv[i].Phh, lv[i].Phl, 1024, GTh, GTl, 1024, lv[i].Pth, lv[i].Ptl, 1024, Ns,
         1024, N, 1024, lv[i].SK);
    reduce(1024, N, lv[i].SK, Ns, 1 | 2, nullptr, nullptr,
           GPh + Ns, GPl + Ns, 4096, GTh + (size_t)Ns * 1024, GTl + (size_t)Ns * 1024, 1024,
           lv[i].POh, lv[i].POl, 1024, lv[i].TOh, lv[i].TOl, 1024, nullptr, 0);
  }
  u16* P32h = PhBh; u16* P32l = PhBl;  // Phat32 = B^32 (normal form)

  // ---- Y = Xb @ Ghat^T : [1024][1024], K=4096; all rows -> planes + f32 ----
  gemm(Xbh, Xbl, 4096, GPh, GPl, 4096, nullptr, nullptr, 0, 1024, 1024, 1024, 4096, 8);
  reduce(1024, 1024, 8, 1024, 1 | 8, nullptr, nullptr,
         Yh, Yl, 1024, nullptr, nullptr, 0, nullptr, nullptr, 0, nullptr, nullptr, 0, Yf, 1024);

  // ---- Horner: h = Y1@P32 + Y0 ----
  gemm(Yh + (size_t)512 * 1024, Yl + (size_t)512 * 1024, 1024,
       P32h, P32l, 1024, nullptr, nullptr, 0, 1024, 512, 1024, 1024, 16);
  reduce(512, 1024, 16, 1024, 1 | 16, nullptr, Yf,
         hph, hpl, 1024, nullptr, nullptr, 0, nullptr, nullptr, 0, nullptr, nullptr, 0, nullptr, 0);

  // ---- readout ----
  gemm(hph, hpl, 1024, W1h, W1l, 1024, nullptr, nullptr, 0, 1024, 512, 1024, 1024, 16);
  reduce(512, 1024, 16, 1024, 1 | 4, b1, nullptr,
         h1h, h1l, 1024, nullptr, nullptr, 0, nullptr, nullptr, 0, nullptr, nullptr, 0, nullptr, 0);
  gemm(h1h, h1l, 1024, W2h, W2l, 1024, nullptr, nullptr, 0, 1024, 512, 1024, 1024, 16);
  reduce(512, 1024, 16, 1024, 8 | 4, b2, nullptr,
         nullptr, nullptr, 0, nullptr, nullptr, 0, nullptr, nullptr, 0, nullptr, nullptr, 0, h2f, 1024);
  laes_final<<<kB, 64, 0, stream>>>(h2f, W3, b3, out);
}